// Round 7
// baseline (106.006 us; speedup 1.0000x reference)
//
#include <hip/hip_runtime.h>
#include <hip/hip_bf16.h>
#include <math.h>

// Problem constants: B=2, C=256, H=W=64 -> HW=4096
#define BB 2
#define CC 256
#define HWN 4096
#define PT 32              // pixels per norm block

// Fragment-blocked fp8 layout (per batch): for row r (pixel), k-byte kb:
//   addr = (r>>4)*4096 + (kb>>5)*512 + (r&15)*32 + (kb&31)
// => an MFMA fragment load (16 rows x 32 k-bytes, lane L: row L&15,
//    kb (L>>4)*32) is ONE contiguous 2KB wave transaction. No LDS needed.

typedef __attribute__((ext_vector_type(4))) int   intx4;
typedef __attribute__((ext_vector_type(8))) int   intx8;
typedef __attribute__((ext_vector_type(4))) float floatx4;

// Kernel 1: per-pixel channel norms + desc/kp partials. One block per
// (batch, 32-pixel chunk), 1024 threads, float4 loads. NO LDS stash, no
// transpose — writes only invn[3][B][HW] (round-6 lesson: the 48KB stash +
// barrier-serialized write tail made prep ~5x its streaming floor).
__global__ __launch_bounds__(1024) void norm_kernel(
    const float* __restrict__ sv, const float* __restrict__ si,
    const float* __restrict__ sf, const float* __restrict__ dv,
    const float* __restrict__ di, const float* __restrict__ df,
    float* __restrict__ invn, float* __restrict__ pk,
    float* __restrict__ pd)
{
    __shared__ float ssq[3][PT];
    __shared__ float sdesc;

    const int b   = blockIdx.x / (HWN / PT);
    const int p0  = (blockIdx.x % (HWN / PT)) * PT;
    const int tid = threadIdx.x;
    const int tp4 = tid & 7;          // 4-pixel group: pixels 4*tp4..+3
    const int c0  = (tid >> 3) * 2;   // channel pair c0, c0+1

    if (tid < 3 * PT) ((float*)ssq)[tid] = 0.0f;
    if (tid == 0) sdesc = 0.0f;
    __syncthreads();

    // Loads: per (channel row, 8 lanes) = 128B contiguous float4 segments.
    const size_t rbase = ((size_t)b * CC + c0) * HWN + p0 + tp4 * 4;
    const floatx4 v0 = *(const floatx4*)(dv + rbase);
    const floatx4 v1 = *(const floatx4*)(dv + rbase + HWN);
    const floatx4 i0 = *(const floatx4*)(di + rbase);
    const floatx4 i1 = *(const floatx4*)(di + rbase + HWN);
    const floatx4 f0 = *(const floatx4*)(df + rbase);
    const floatx4 f1 = *(const floatx4*)(df + rbase + HWN);

    float sqv[4], sqi[4], sqf[4], descp = 0.f;
    #pragma unroll
    for (int k = 0; k < 4; ++k) {
        sqv[k] = v0[k] * v0[k] + v1[k] * v1[k];
        sqi[k] = i0[k] * i0[k] + i1[k] * i1[k];
        sqf[k] = f0[k] * f0[k] + f1[k] * f1[k];
        descp += fabsf(f0[k] - 0.5f * (v0[k] + i0[k]))
               + fabsf(f1[k] - 0.5f * (v1[k] + i1[k]));
    }

    // Reduce squares across the 8 channel-pair lanes sharing a pixel group.
    #pragma unroll
    for (int off = 8; off < 64; off <<= 1) {
        #pragma unroll
        for (int k = 0; k < 4; ++k) {
            sqv[k] += __shfl_down(sqv[k], off);
            sqi[k] += __shfl_down(sqi[k], off);
            sqf[k] += __shfl_down(sqf[k], off);
        }
    }
    if ((tid & 63) < 8) {
        #pragma unroll
        for (int k = 0; k < 4; ++k) {
            atomicAdd(&ssq[0][tp4 * 4 + k], sqv[k]);
            atomicAdd(&ssq[1][tp4 * 4 + k], sqi[k]);
            atomicAdd(&ssq[2][tp4 * 4 + k], sqf[k]);
        }
    }

    // desc partial: wave reduce, one LDS atomic per wave
    #pragma unroll
    for (int off = 32; off > 0; off >>= 1) descp += __shfl_down(descp, off);
    if ((tid & 63) == 0) atomicAdd(&sdesc, descp);

    // kp term: this block's 32 pixels (first wave only)
    if (tid < 64) {
        float kpv = 0.f;
        if (tid < PT) {
            const size_t sidx = (size_t)b * HWN + p0 + tid;
            kpv = fabsf(sf[sidx] - fmaxf(sv[sidx], si[sidx]));
        }
        #pragma unroll
        for (int off = 32; off > 0; off >>= 1) kpv += __shfl_down(kpv, off);
        if (tid == 0) pk[blockIdx.x] = kpv;
    }
    __syncthreads();

    if (tid < 3 * PT) {
        const int t = tid >> 5, p = tid & 31;
        const float s = ((float*)ssq)[tid];
        invn[t * (BB * HWN) + b * HWN + p0 + p] =
            1.0f / fmaxf(sqrtf(s), 1e-12f);
    }
    if (tid == 0) pd[blockIdx.x] = sdesc;
}

// Kernel 2: streaming normalize + fp8 pack into fragment-blocked layout.
// Grid (HW/16, 2, B) x 256 threads = 1024 blocks (4/CU), zero LDS, zero
// barriers. Each wave handles 16 pixels x 32 channels; writes are 64
// consecutive ints per wave-instr (256B contiguous). Reads are 32B-segment
// strided but L2/L3-warm from kernel 1.
__global__ __launch_bounds__(256) void pack_kernel(
    const float* __restrict__ dv, const float* __restrict__ di,
    const float* __restrict__ df, const float* __restrict__ invn,
    unsigned char* __restrict__ Af8, unsigned char* __restrict__ Df8)
{
    const int pg0  = blockIdx.x * 16;        // pixel group base (16 pixels)
    const int h    = blockIdx.y;             // channel half
    const int b    = blockIdx.z;
    const int tid  = threadIdx.x;
    const int wave = tid >> 6;
    const int lane = tid & 63;
    const int kb   = h * 4 + wave;           // 32-channel block index 0..7
    const int cg   = lane & 7;               // int slot: channels kb*32+cg*4..+3
    const int pr   = lane >> 3;              // pixel sub-slot 0..7

    const int c0 = kb * 32 + cg * 4;
    const float* dvb = dv + ((size_t)b * CC + c0) * HWN;
    const float* dib = di + ((size_t)b * CC + c0) * HWN;
    const float* dfb = df + ((size_t)b * CC + c0) * HWN;
    int* Ao = (int*)(Af8 + (size_t)b * HWN * CC);
    int* Do = (int*)(Df8 + (size_t)b * HWN * CC);
    const int obase = (pg0 >> 4) * 1024 + kb * 128;

    #pragma unroll
    for (int s = 0; s < 2; ++s) {
        const int P = pg0 + pr + s * 8;
        const float ia = invn[0 * (BB * HWN) + b * HWN + P];
        const float ib = invn[1 * (BB * HWN) + b * HWN + P];
        const float ic = invn[2 * (BB * HWN) + b * HWN + P];
        float a[4], d[4];
        #pragma unroll
        for (int j = 0; j < 4; ++j) {
            const size_t idx = (size_t)j * HWN + P;
            a[j] = dvb[idx] * ia;
            d[j] = dfb[idx] * ic - dib[idx] * ib;
        }
        int wa = __builtin_amdgcn_cvt_pk_fp8_f32(a[0], a[1], 0, false);
        wa     = __builtin_amdgcn_cvt_pk_fp8_f32(a[2], a[3], wa, true);
        int wd = __builtin_amdgcn_cvt_pk_fp8_f32(d[0], d[1], 0, false);
        wd     = __builtin_amdgcn_cvt_pk_fp8_f32(d[2], d[3], wd, true);
        const int oidx = obase + (pr + s * 8) * 8 + cg;  // = obase+s*64+lane
        Ao[oidx] = wa;
        Do[oidx] = wd;
    }
}

// No-LDS GEMM (unchanged from round 6): one 64x64 tile per wave, fragments
// loaded as 2KB contiguous wave transactions, 32 MFMA, zero barriers.
// |.|-sum epilogue (permutation-invariant) -> per-wave partial store.
__global__ __launch_bounds__(256) void gemm_abs_kernel(
    const unsigned char* __restrict__ Af8,
    const unsigned char* __restrict__ Df8,
    float* __restrict__ pg)
{
    const int b    = blockIdx.z;
    const int tid  = threadIdx.x;
    const int wave = tid >> 6;
    const int lane = tid & 63;
    const int wr   = wave >> 1, wc = wave & 1;
    const int mg0  = blockIdx.x * 8 + wr * 4;   // row-group (of 16) base
    const int ng0  = blockIdx.y * 8 + wc * 4;

    const unsigned char* Ab = Af8 + (size_t)b * HWN * CC;
    const unsigned char* Db = Df8 + (size_t)b * HWN * CC;
    const int lofs = (lane >> 4) * 512 + (lane & 15) * 32;

    intx4 a[4][2][2], bb[4][2][2];
    #pragma unroll
    for (int mi = 0; mi < 4; ++mi)
        #pragma unroll
        for (int ks = 0; ks < 2; ++ks) {
            const unsigned char* pa = Ab + (size_t)(mg0 + mi) * 4096
                                    + ks * 2048 + lofs;
            a[mi][ks][0] = *(const intx4*)(pa);
            a[mi][ks][1] = *(const intx4*)(pa + 16);
        }
    #pragma unroll
    for (int ni = 0; ni < 4; ++ni)
        #pragma unroll
        for (int ks = 0; ks < 2; ++ks) {
            const unsigned char* pb = Db + (size_t)(ng0 + ni) * 4096
                                    + ks * 2048 + lofs;
            bb[ni][ks][0] = *(const intx4*)(pb);
            bb[ni][ks][1] = *(const intx4*)(pb + 16);
        }

    floatx4 accf[4][4];
    #pragma unroll
    for (int mi = 0; mi < 4; ++mi)
        #pragma unroll
        for (int ni = 0; ni < 4; ++ni)
            accf[mi][ni] = (floatx4){0.f, 0.f, 0.f, 0.f};

    #pragma unroll
    for (int ks = 0; ks < 2; ++ks)
        #pragma unroll
        for (int mi = 0; mi < 4; ++mi) {
            const intx8 a8 = __builtin_shufflevector(
                a[mi][ks][0], a[mi][ks][1], 0, 1, 2, 3, 4, 5, 6, 7);
            #pragma unroll
            for (int ni = 0; ni < 4; ++ni) {
                const intx8 b8 = __builtin_shufflevector(
                    bb[ni][ks][0], bb[ni][ks][1], 0, 1, 2, 3, 4, 5, 6, 7);
                accf[mi][ni] = __builtin_amdgcn_mfma_scale_f32_16x16x128_f8f6f4(
                    a8, b8, accf[mi][ni],
                    0, 0,                      // cbsz=fp8, blgp=fp8
                    0, 0x7F7F7F7F,             // A scales: E8M0 1.0
                    0, 0x7F7F7F7F);            // B scales: E8M0 1.0
            }
        }

    float s = 0.f;
    #pragma unroll
    for (int mi = 0; mi < 4; ++mi)
        #pragma unroll
        for (int ni = 0; ni < 4; ++ni)
            #pragma unroll
            for (int r = 0; r < 4; ++r)
                s += fabsf(accf[mi][ni][r]);
    #pragma unroll
    for (int off = 32; off > 0; off >>= 1) s += __shfl_down(s, off);
    if (lane == 0) {
        const int flat = blockIdx.x + 32 * (blockIdx.y + 32 * blockIdx.z);
        pg[flat * 4 + wave] = s;   // per-wave partial, zero contention
    }
}

// Single block: reduce 8192 match partials + 256 kp + 256 desc partials.
__global__ __launch_bounds__(256) void final_kernel(
    const float* __restrict__ pg, const float* __restrict__ pk,
    const float* __restrict__ pd, float* __restrict__ out)
{
    __shared__ float ws[4];
    const int t = threadIdx.x;
    float s = 0.f;
    #pragma unroll
    for (int i = 0; i < 32; ++i)
        s += pg[t + i * 256];
    s *= (1.0f / 33554432.0f);                 // match / (B*HW*HW)
    s += pk[t] * (1.0f / 8192.0f)              // kp / (B*HW)
       + pd[t] * (1.0f / 2097152.0f);          // desc / (B*C*HW)
    #pragma unroll
    for (int off = 32; off > 0; off >>= 1) s += __shfl_down(s, off);
    if ((t & 63) == 0) ws[t >> 6] = s;
    __syncthreads();
    if (t == 0) out[0] = ws[0] + ws[1] + ws[2] + ws[3];
}

extern "C" void kernel_launch(void* const* d_in, const int* in_sizes, int n_in,
                              void* d_out, int out_size, void* d_ws, size_t ws_size,
                              hipStream_t stream) {
    const float* sv = (const float*)d_in[0];
    const float* si = (const float*)d_in[1];
    const float* sf = (const float*)d_in[2];
    const float* dv = (const float*)d_in[3];
    const float* di = (const float*)d_in[4];
    const float* df = (const float*)d_in[5];

    unsigned char* Af8 = (unsigned char*)d_ws;                 // 2 MB
    unsigned char* Df8 = Af8 + (size_t)BB * HWN * CC;          // 2 MB
    float* pg   = (float*)(Df8 + (size_t)BB * HWN * CC);       // 32 KB (8192)
    float* pk   = pg + 8192;                                   // 1 KB (256)
    float* pd   = pk + 256;                                    // 1 KB (256)
    float* invn = pd + 256;                                    // 96 KB (3*2*4096)

    norm_kernel<<<dim3(BB * (HWN / PT)), 1024, 0, stream>>>(
        sv, si, sf, dv, di, df, invn, pk, pd);
    pack_kernel<<<dim3(HWN / 16, 2, BB), 256, 0, stream>>>(
        dv, di, df, invn, Af8, Df8);
    gemm_abs_kernel<<<dim3(HWN / 128, HWN / 128, BB), 256, 0, stream>>>(
        Af8, Df8, pg);
    final_kernel<<<1, 256, 0, stream>>>(pg, pk, pd, (float*)d_out);
}